// Round 8
// baseline (207.888 us; speedup 1.0000x reference)
//
#include <hip/hip_runtime.h>

// RNN car-following: NVEH=16384, NT=256, H=20.
// R16 (resubmit; previous round was an infra failure, no signal):
// R15 (lag-rq + biasK-in-A, both numerically validated) + UNROLL-2
// + issue micro-cuts. Model from R11/R13/R15 deltas: wall ~ issue(810cy)
// + ~440cy distributed bubbles (MFMA latency hole, phase-transition
// shadows, glue); chain cuts within one iteration pay 0 (R15), issue
// cuts pay ~1:0.7 (R13). At 1 wave/SIMD the only independent bubble
// filler is the ADJACENT timestep's slack work (lag-rq residual path,
// store, xv glue) — the compiler can only schedule it across steps if
// both steps are in one region: #pragma unroll 2 on the t-loop.
// Micro-cuts (bit-identical rounding points):
//  - hh = fma(-ec, Roc, Roc)   (scalar neg modifier, -1 op/item)
//  - unconditional Bf[6] insert: xv select chain yields 1.0 for q==3
//    (f2bf(1.0)=0x3F80) -> no exec-mask flip around the insert.
// NO packed-fp32 (R14 failed), NO asm cvt_pk (next single-variable try).

#define NVEH 16384
#define NT   256
#define H    20

typedef float f32x4  __attribute__((ext_vector_type(4)));
typedef short bf16x8 __attribute__((ext_vector_type(8)));

#if __has_builtin(__builtin_amdgcn_exp2f)
#define EXP2(x) __builtin_amdgcn_exp2f(x)
#else
#define EXP2(x) __expf((x) * 0.69314718056f)
#endif
#define RCP(x) __builtin_amdgcn_rcpf(x)

__device__ __forceinline__ short f2bf(float f) {     // RNE float->bf16
    unsigned u = __builtin_bit_cast(unsigned, f);
    u += 0x7fffu + ((u >> 16) & 1u);
    return (short)(u >> 16);
}
__device__ __forceinline__ float bf2f(short s) {
    return __builtin_bit_cast(float, ((unsigned)(unsigned short)s) << 16);
}

__global__ __launch_bounds__(256, 1) void rnncf_kernel(
    const float* __restrict__ lead,   // (NVEH, NT, 2)
    const float* __restrict__ inits,  // (NVEH, 2)
    const float* __restrict__ h0,     // (NVEH, H)
    const float* __restrict__ c0,     // (NVEH, H)
    const float* __restrict__ W,      // (3, 80)
    const float* __restrict__ U,      // (20, 80)
    const float* __restrict__ b,      // (80,)
    const float* __restrict__ Wd,     // (20,)
    const float* __restrict__ bd,     // (1,)
    float* __restrict__ out)
{
    // UT: 6 tiles x 16 rows x 32 k (bf16). Gate tiles T=0..4: row m =
    // gate(m&3) of item j=5*(m>>2)+T, scaled log2e (2log2e for g), with
    // the rank-1 wcn correction folded in: A' = A_scaled - wcn_row * a5.
    //   ko<5  -> U[5kq+ko][col]*scale - wcn*7*Wd[5kq+ko]
    //   ko==5 -> -wcn
    //   ko==6 -> kq<3 ? W[kq][col]*scale : b[col]*scale - wcn*biasK
    //   ko==7 -> 0
    // Tile 5 (acc row a5), rows with (m&3)==0: ko<5 -> 7*Wd[5kq+ko],
    // ko==5 -> 1.0, (kq3,ko6) -> bf16(biasK) [hi], (kq3,ko7) -> biasK
    // residual (B one-slots at q=3: Bf[6]=Bf[7]=1.0). Other rows 0.
    __shared__ __attribute__((aligned(16))) short UT[96 * 32];

    const int tid  = threadIdx.x;
    const int lane = tid & 63;
    const int q    = lane >> 4;       // k-window / item-group
    const int c    = lane & 15;       // vehicle column
    const float L2E = 1.44269504f;
    const float N2L = -2.f * L2E;     // -2*log2(e)
    const float P2L =  2.f * L2E;
    const float IN2L = -0.34657359028f;   // 1/N2L
    const float bdv = bd[0];
    const float biasK = 7.f * bdv - 4.f;

    // ---- build UT (wcn folded into gate tiles; biasK in a5) ----
    for (int idx = tid; idx < 96 * 32; idx += 256) {
        int row = idx >> 5, k = idx & 31;
        int T = row >> 4, m = row & 15;
        int kq = k >> 3, ko = k & 7;
        float v = 0.f;
        if (T < 5) {
            int g = m & 3, j = 5 * (m >> 2) + T;
            int col = g * 20 + j;
            float scale = (g == 2) ? (2.f * L2E) : L2E;
            float wcn = -(-0.001f * W[col] + 0.0025f * W[80 + col]) * scale;
            if      (ko < 5)             v = U[(5 * kq + ko) * 80 + col] * scale
                                           - wcn * 7.f * Wd[5 * kq + ko];
            else if (ko == 5)            v = -wcn;
            else if (ko == 6 && kq < 3)  v = W[kq * 80 + col] * scale;
            else if (ko == 6)            v = b[col] * scale - wcn * biasK;
        } else if ((m & 3) == 0) {
            if      (ko < 5)             v = 7.f * Wd[5 * kq + ko];
            else if (ko == 5)            v = 1.f;
            else if (kq == 3 && ko == 6) v = biasK;                      // hi (f2bf below)
            else if (kq == 3 && ko == 7) v = biasK - bf2f(f2bf(biasK));  // residual
        }
        UT[idx] = f2bf(v);
    }

    const int veh = blockIdx.x * 64 + (tid >> 6) * 16 + c;

    // ---- per-item constants: items j = 5q+T ----
    float wd7[5], w7b[5];
#pragma unroll
    for (int T = 0; T < 5; ++T) {
        float w7 = 7.f * Wd[5 * q + T];
        wd7[T] = w7;
        w7b[T] = bf2f(f2bf(w7));
    }

    // ---- init: h0 -> B-frag, res partial, acc_{-1}; c0 -> scaled ----
    bf16x8 Bf = {0, 0, 0, 0, 0, 0, 0, 0};
    float cst2[5], hl[5];
    float rpart = 0.f, apart = 0.f;
#pragma unroll
    for (int T = 0; T < 5; ++T) {
        int j = 5 * q + T;
        float hv = h0[veh * H + j];
        cst2[T] = N2L * c0[veh * H + j];
        hl[T] = hv;
        short hb = f2bf(hv);
        float hi = bf2f(hb);
        Bf[T] = hb;
        rpart = __builtin_fmaf(hv, wd7[T], rpart);
        rpart = __builtin_fmaf(-hi, w7b[T], rpart);
        apart = __builtin_fmaf(hv, wd7[T], apart);
    }
    short rqb = f2bf(rpart);          // lag-rq carry
    Bf[5] = rqb;
    apart += __shfl_xor(apart, 16);
    apart += __shfl_xor(apart, 32);

    float pos = inits[veh * 2 + 0];
    float spd = inits[veh * 2 + 1];
    {
        float a = apart + biasK;          // acc_{-1}, exact fp32
        pos -= 0.1f * a;                  // virtual lagged state
        spd -= 0.1f * a;
    }

    // ---- x~_0 and lead pipeline (depth 2) ----
    const float2* lp0 = (const float2*)lead + (long)veh * NT;
    {
        float2 lu = lp0[0];
        float xv = (q == 0) ? (lu.x - pos) * 0.01f
                 : (q == 1) ? spd * 0.025f
                 : (q == 2) ? lu.y * 0.025f : 1.0f;
        Bf[6] = f2bf(xv);
        if (q == 3) Bf[7] = (short)0x3F80;  // second one-slot (biasK row)
    }
    float2 lA = lp0[1];
    float2 lB = lp0[2];

    __syncthreads();   // UT visibility; only barrier in the kernel

    // ---- loop-invariant A fragments (row c, k-slice q) ----
    bf16x8 A[6];
#pragma unroll
    for (int T = 0; T < 6; ++T)
        A[T] = *(const bf16x8*)&UT[(T * 16 + c) * 32 + q * 8];

#pragma unroll 2
    for (int t = 0; t < NT; ++t) {
        float2 lu = lA;                   // lead[t+1], loaded 2 iters ago
        lA = lB;
        int tn = t + 3; tn = (tn < NT) ? tn : NT - 1;
        lB = lp0[tn];                     // consumed 2 iters from now

        f32x4 zero = {0.f, 0.f, 0.f, 0.f};
        // acc tile FIRST: everything downstream gates on z5[0]
        f32x4 z5 = __builtin_amdgcn_mfma_f32_16x16x32_bf16(A[5], Bf, zero, 0, 0, 0);
        f32x4 z[5];
#pragma unroll
        for (int T = 0; T < 5; ++T)
            z[T] = __builtin_amdgcn_mfma_f32_16x16x32_bf16(A[T], Bf, zero, 0, 0, 0);

        // ---- acc_{t-1}: every lane (biasK pre-folded into a5) ----
        float acc = z5[0];
        pos = __builtin_fmaf(0.1f, acc, pos);
        spd = __builtin_fmaf(0.1f, acc, spd);
        if (q == 1 && t > 0)
            out[(size_t)(t - 1) * NVEH + veh] = pos;   // coalesced

        // ---- x~_{t+1} into own B-frag slot (unconditional insert) ----
        {
            float xv = (q == 0) ? (lu.x - pos) * 0.01f
                     : (q == 1) ? spd * 0.025f
                     : (q == 2) ? lu.y * 0.025f : 1.0f;
            Bf[6] = f2bf(xv);
        }

        // ---- 5 items (j=5q+T): gates lane-local, correction pre-folded ----
        float r[5];
#pragma unroll
        for (int T = 0; T < 5; ++T) {
            float ei = EXP2(-z[T][0]);    // e^{-i_eff}
            float ef = EXP2(-z[T][1]);    // e^{-f_eff}
            float eg = EXP2(-z[T][2]);    // e^{-2g_eff}
            float eo = EXP2(-z[T][3]);    // e^{-o_eff}
            float pi = 1.f + ei, pf = 1.f + ef, pg = 1.f + eg, po = 1.f + eo;
            float pig = pi * pg;
            float R3  = RCP(pf * pig);    // 1/(pf*pi*pg)
            float uu  = __builtin_fmaf(P2L, eg, N2L);         // N2L*(1-eg)
            float c2  = R3 * __builtin_fmaf(pig, cst2[T], uu * pf);
            cst2[T] = c2;                                     // scaled c
            float ec  = EXP2(__builtin_fminf(c2, 80.f));      // e^{-2c}
            float Roc = RCP(po * (1.f + ec));
            float hh  = __builtin_fmaf(-ec, Roc, Roc);        // (1-ec)*Roc
            hl[T] = hh;
            unsigned u = __builtin_bit_cast(unsigned, hh);
            unsigned rr = u + 0x7fffu + ((u >> 16) & 1u);     // RNE
            Bf[T] = (short)(rr >> 16);
            float hi = __builtin_bit_cast(float, rr & 0xffff0000u);
            r[T] = __builtin_fmaf(hh, wd7[T], -(hi * w7b[T]));
        }
        // ---- lag-rq: insert PREVIOUS step's rq; this step's rq has a
        // full iteration of slack (unroll-2 lets the scheduler sink it
        // into the next step's MFMA-latency hole) ----
        Bf[5] = rqb;
        float rq = ((r[0] + r[1]) + (r[2] + r[3])) + r[4];
        rqb = f2bf(rq);
    }

    // ---- tail: acc_255 exact from fp32 hl ----
    float ap = 0.f;
#pragma unroll
    for (int T = 0; T < 5; ++T) ap = __builtin_fmaf(hl[T], wd7[T], ap);
    ap += __shfl_xor(ap, 16);
    ap += __shfl_xor(ap, 32);
    float accF = ap + biasK;
    if (q == 1) out[(size_t)(NT - 1) * NVEH + veh] = pos + 0.1f * accF;
    if (q == 2) out[(size_t)NT * NVEH + veh]       = spd + 0.1f * accF;

    // ---- final h, c (c unscaled from cst2) ----
    const int oH = NT * NVEH + NVEH;
    const int oC = oH + NVEH * H;
#pragma unroll
    for (int T = 0; T < 5; ++T) {
        int j = 5 * q + T;
        out[oH + veh * H + j] = hl[T];
        out[oC + veh * H + j] = cst2[T] * IN2L;
    }
}

extern "C" void kernel_launch(void* const* d_in, const int* in_sizes, int n_in,
                              void* d_out, int out_size, void* d_ws, size_t ws_size,
                              hipStream_t stream) {
    const float* lead  = (const float*)d_in[0];
    const float* inits = (const float*)d_in[1];
    const float* h0    = (const float*)d_in[2];
    const float* c0    = (const float*)d_in[3];
    const float* W     = (const float*)d_in[4];
    const float* U     = (const float*)d_in[5];
    const float* b     = (const float*)d_in[6];
    const float* Wd    = (const float*)d_in[7];
    const float* bd    = (const float*)d_in[8];
    float* out = (float*)d_out;

    rnncf_kernel<<<NVEH / 64, 256, 0, stream>>>(lead, inits, h0, c0, W, U, b, Wd, bd, out);
}

// Round 9
// 202.145 us; speedup vs baseline: 1.0284x; 1.0284x over previous
//
#include <hip/hip_runtime.h>

// RNN car-following: NVEH=16384, NT=256, H=20.
// R17: EXACT R13 revert (the 133.5us best) + one pure op-removal.
// Eight-round evidence: issue cuts preserving the R9/R13 structure pay
// ~0.7 wall/issue (R11 -6us, R13 -8.5us); EVERY schedule perturbation
// loses (R10 asm cvt_pk +10us, R12 exact-acc/shfl-chain +16us, R15
// chain-cuts +2.4us, R16 unroll-2 +5.7us with busy flat -> pure added
// stall). The compiler's single-iteration schedule of this body is a
// local optimum; residual ~35% stall is distributed MFMA/trans latency,
// unfillable at 1 wave/SIMD (occupancy structurally pinned: 1024 waves
// tile 1024 SIMDs; item-split across waves re-adds the fatal LDS
// round-trip, R5-R8/R12).
// Single change vs R13: hh = fma(-ec, Roc, Roc) for (1-ec)*Roc
// (sub+mul -> fma, -1 op/item; <=1 fp32 ulp, absorbed by bf16 round).

#define NVEH 16384
#define NT   256
#define H    20

typedef float f32x4  __attribute__((ext_vector_type(4)));
typedef short bf16x8 __attribute__((ext_vector_type(8)));

#if __has_builtin(__builtin_amdgcn_exp2f)
#define EXP2(x) __builtin_amdgcn_exp2f(x)
#else
#define EXP2(x) __expf((x) * 0.69314718056f)
#endif
#define RCP(x) __builtin_amdgcn_rcpf(x)

__device__ __forceinline__ short f2bf(float f) {     // RNE float->bf16
    unsigned u = __builtin_bit_cast(unsigned, f);
    u += 0x7fffu + ((u >> 16) & 1u);
    return (short)(u >> 16);
}
__device__ __forceinline__ float bf2f(short s) {
    return __builtin_bit_cast(float, ((unsigned)(unsigned short)s) << 16);
}

__global__ __launch_bounds__(256, 1) void rnncf_kernel(
    const float* __restrict__ lead,   // (NVEH, NT, 2)
    const float* __restrict__ inits,  // (NVEH, 2)
    const float* __restrict__ h0,     // (NVEH, H)
    const float* __restrict__ c0,     // (NVEH, H)
    const float* __restrict__ W,      // (3, 80)
    const float* __restrict__ U,      // (20, 80)
    const float* __restrict__ b,      // (80,)
    const float* __restrict__ Wd,     // (20,)
    const float* __restrict__ bd,     // (1,)
    float* __restrict__ out)
{
    // UT: 6 tiles x 16 rows x 32 k (bf16). Gate tiles T=0..4: row m =
    // gate(m&3) of item j=5*(m>>2)+T, scaled log2e (2log2e for g), with
    // the rank-1 wcn correction folded in: A' = A_scaled - wcn_row * a5.
    //   ko<5  -> U[5kq+ko][col]*scale - wcn*7*Wd[5kq+ko]
    //   ko==5 -> -wcn
    //   ko==6 -> kq<3 ? W[kq][col]*scale : b[col]*scale - wcn*biasK
    //   ko==7 -> 0
    // Tile 5 (acc row a5), rows with (m&3)==0: ko<5 -> 7*Wd[5kq+ko],
    // ko==5 -> 1.0, else 0 (biasK added in fp32). Other rows 0.
    __shared__ __attribute__((aligned(16))) short UT[96 * 32];

    const int tid  = threadIdx.x;
    const int lane = tid & 63;
    const int q    = lane >> 4;       // k-window / item-group
    const int c    = lane & 15;       // vehicle column
    const float L2E = 1.44269504f;
    const float N2L = -2.f * L2E;     // -2*log2(e)
    const float P2L =  2.f * L2E;
    const float IN2L = -0.34657359028f;   // 1/N2L
    const float bdv = bd[0];
    const float biasK = 7.f * bdv - 4.f;

    // ---- build UT (wcn folded into gate tiles) ----
    for (int idx = tid; idx < 96 * 32; idx += 256) {
        int row = idx >> 5, k = idx & 31;
        int T = row >> 4, m = row & 15;
        int kq = k >> 3, ko = k & 7;
        float v = 0.f;
        if (T < 5) {
            int g = m & 3, j = 5 * (m >> 2) + T;
            int col = g * 20 + j;
            float scale = (g == 2) ? (2.f * L2E) : L2E;
            float wcn = -(-0.001f * W[col] + 0.0025f * W[80 + col]) * scale;
            if      (ko < 5)             v = U[(5 * kq + ko) * 80 + col] * scale
                                           - wcn * 7.f * Wd[5 * kq + ko];
            else if (ko == 5)            v = -wcn;
            else if (ko == 6 && kq < 3)  v = W[kq * 80 + col] * scale;
            else if (ko == 6)            v = b[col] * scale - wcn * biasK;
        } else if ((m & 3) == 0) {
            if      (ko < 5)  v = 7.f * Wd[5 * kq + ko];
            else if (ko == 5) v = 1.f;
        }
        UT[idx] = f2bf(v);
    }

    const int veh = blockIdx.x * 64 + (tid >> 6) * 16 + c;

    // ---- per-item constants: items j = 5q+T ----
    float wd7[5], w7b[5];
#pragma unroll
    for (int T = 0; T < 5; ++T) {
        float w7 = 7.f * Wd[5 * q + T];
        wd7[T] = w7;
        w7b[T] = bf2f(f2bf(w7));
    }

    // ---- init: h0 -> B-frag, res partial, acc_{-1}; c0 -> scaled ----
    bf16x8 Bf = {0, 0, 0, 0, 0, 0, 0, 0};
    float cst2[5], hl[5];
    float rpart = 0.f, apart = 0.f;
#pragma unroll
    for (int T = 0; T < 5; ++T) {
        int j = 5 * q + T;
        float hv = h0[veh * H + j];
        cst2[T] = N2L * c0[veh * H + j];
        hl[T] = hv;
        short hb = f2bf(hv);
        float hi = bf2f(hb);
        Bf[T] = hb;
        rpart = __builtin_fmaf(hv, wd7[T], rpart);
        rpart = __builtin_fmaf(-hi, w7b[T], rpart);
        apart = __builtin_fmaf(hv, wd7[T], apart);
    }
    Bf[5] = f2bf(rpart);
    apart += __shfl_xor(apart, 16);
    apart += __shfl_xor(apart, 32);

    float pos = inits[veh * 2 + 0];
    float spd = inits[veh * 2 + 1];
    {
        float a = apart + biasK;          // acc_{-1}, exact fp32
        pos -= 0.1f * a;                  // virtual lagged state
        spd -= 0.1f * a;
    }

    // ---- x~_0 and lead pipeline (depth 2) ----
    const float2* lp0 = (const float2*)lead + (long)veh * NT;
    {
        float2 lu = lp0[0];
        float xv = (q == 0) ? (lu.x - pos) * 0.01f
                 : (q == 1) ? spd * 0.025f
                            : lu.y * 0.025f;
        if (q < 3) Bf[6] = f2bf(xv);
        else       Bf[6] = (short)0x3F80;   // one-slot (1.0 bf16)
    }
    float2 lA = lp0[1];
    float2 lB = lp0[2];

    __syncthreads();   // UT visibility; only barrier in the kernel

    // ---- loop-invariant A fragments (row c, k-slice q) ----
    bf16x8 A[6];
#pragma unroll
    for (int T = 0; T < 6; ++T)
        A[T] = *(const bf16x8*)&UT[(T * 16 + c) * 32 + q * 8];

    for (int t = 0; t < NT; ++t) {
        float2 lu = lA;                   // lead[t+1], loaded 2 iters ago
        lA = lB;
        int tn = t + 3; tn = (tn < NT) ? tn : NT - 1;
        lB = lp0[tn];                     // consumed 2 iters from now

        f32x4 zero = {0.f, 0.f, 0.f, 0.f};
        // acc tile FIRST: everything downstream gates on z5[0]
        f32x4 z5 = __builtin_amdgcn_mfma_f32_16x16x32_bf16(A[5], Bf, zero, 0, 0, 0);
        f32x4 z[5];
#pragma unroll
        for (int T = 0; T < 5; ++T)
            z[T] = __builtin_amdgcn_mfma_f32_16x16x32_bf16(A[T], Bf, zero, 0, 0, 0);

        // ---- acc_{t-1}: every lane, fp32-accurate ----
        float acc = z5[0] + biasK;
        pos = __builtin_fmaf(0.1f, acc, pos);
        spd = __builtin_fmaf(0.1f, acc, spd);
        if (q == 1 && t > 0)
            out[(size_t)(t - 1) * NVEH + veh] = pos;   // coalesced

        // ---- x~_{t+1} into own B-frag slot ----
        {
            float xv = (q == 0) ? (lu.x - pos) * 0.01f
                     : (q == 1) ? spd * 0.025f
                                : lu.y * 0.025f;
            if (q < 3) Bf[6] = f2bf(xv);
        }

        // ---- 5 items (j=5q+T): gates lane-local, correction pre-folded ----
        float r[5];
#pragma unroll
        for (int T = 0; T < 5; ++T) {
            float ei = EXP2(-z[T][0]);    // e^{-i_eff}
            float ef = EXP2(-z[T][1]);    // e^{-f_eff}
            float eg = EXP2(-z[T][2]);    // e^{-2g_eff}
            float eo = EXP2(-z[T][3]);    // e^{-o_eff}
            float pi = 1.f + ei, pf = 1.f + ef, pg = 1.f + eg, po = 1.f + eo;
            float pig = pi * pg;
            float R3  = RCP(pf * pig);    // 1/(pf*pi*pg)
            float uu  = __builtin_fmaf(P2L, eg, N2L);         // N2L*(1-eg)
            float c2  = R3 * __builtin_fmaf(pig, cst2[T], uu * pf);
            cst2[T] = c2;                                     // scaled c
            float ec  = EXP2(__builtin_fminf(c2, 80.f));      // e^{-2c}
            float Roc = RCP(po * (1.f + ec));
            float hh  = __builtin_fmaf(-ec, Roc, Roc);        // (1-ec)*Roc
            hl[T] = hh;
            unsigned u = __builtin_bit_cast(unsigned, hh);
            unsigned rr = u + 0x7fffu + ((u >> 16) & 1u);     // RNE
            Bf[T] = (short)(rr >> 16);
            float hi = __builtin_bit_cast(float, rr & 0xffff0000u);
            r[T] = __builtin_fmaf(hh, wd7[T], -(hi * w7b[T]));
        }
        float rq = ((r[0] + r[1]) + (r[2] + r[3])) + r[4];
        Bf[5] = f2bf(rq);
    }

    // ---- tail: acc_255 exact from fp32 hl ----
    float ap = 0.f;
#pragma unroll
    for (int T = 0; T < 5; ++T) ap = __builtin_fmaf(hl[T], wd7[T], ap);
    ap += __shfl_xor(ap, 16);
    ap += __shfl_xor(ap, 32);
    float accF = ap + biasK;
    if (q == 1) out[(size_t)(NT - 1) * NVEH + veh] = pos + 0.1f * accF;
    if (q == 2) out[(size_t)NT * NVEH + veh]       = spd + 0.1f * accF;

    // ---- final h, c (c unscaled from cst2) ----
    const int oH = NT * NVEH + NVEH;
    const int oC = oH + NVEH * H;
#pragma unroll
    for (int T = 0; T < 5; ++T) {
        int j = 5 * q + T;
        out[oH + veh * H + j] = hl[T];
        out[oC + veh * H + j] = cst2[T] * IN2L;
    }
}

extern "C" void kernel_launch(void* const* d_in, const int* in_sizes, int n_in,
                              void* d_out, int out_size, void* d_ws, size_t ws_size,
                              hipStream_t stream) {
    const float* lead  = (const float*)d_in[0];
    const float* inits = (const float*)d_in[1];
    const float* h0    = (const float*)d_in[2];
    const float* c0    = (const float*)d_in[3];
    const float* W     = (const float*)d_in[4];
    const float* U     = (const float*)d_in[5];
    const float* b     = (const float*)d_in[6];
    const float* Wd    = (const float*)d_in[7];
    const float* bd    = (const float*)d_in[8];
    float* out = (float*)d_out;

    rnncf_kernel<<<NVEH / 64, 256, 0, stream>>>(lead, inits, h0, c0, W, U, b, Wd, bd, out);
}

// Round 10
// 200.712 us; speedup vs baseline: 1.0358x; 1.0071x over previous
//
#include <hip/hip_runtime.h>

// RNN car-following: NVEH=16384, NT=256, H=20.
// FINAL (= R13, the session best at 133.5us): rank-1 wcn fold into A,
// lag pipeline, tile-5 bf16-dot acc + rq residual, R3 rcp fusion,
// scaled-c domain. Session evidence (R10-R17): issue cuts preserving
// this structure win (~0.7 wall/issue-cy); EVERY schedule perturbation
// loses (asm cvt_pk +10us, exact-acc/shfl +16us, chain-cuts +2.4us,
// unroll-2 +5.7us, even a single sub+mul->fma swap +2.6us).
// Structural floor: 1 wave/SIMD exactly (1024 waves tile 1024 SIMDs);
// 25 exp/step algorithmic minimum; stalls unfillable (no co-resident
// independent work; item-split re-adds fatal LDS round-trip).

#define NVEH 16384
#define NT   256
#define H    20

typedef float f32x4  __attribute__((ext_vector_type(4)));
typedef short bf16x8 __attribute__((ext_vector_type(8)));

#if __has_builtin(__builtin_amdgcn_exp2f)
#define EXP2(x) __builtin_amdgcn_exp2f(x)
#else
#define EXP2(x) __expf((x) * 0.69314718056f)
#endif
#define RCP(x) __builtin_amdgcn_rcpf(x)

__device__ __forceinline__ short f2bf(float f) {     // RNE float->bf16
    unsigned u = __builtin_bit_cast(unsigned, f);
    u += 0x7fffu + ((u >> 16) & 1u);
    return (short)(u >> 16);
}
__device__ __forceinline__ float bf2f(short s) {
    return __builtin_bit_cast(float, ((unsigned)(unsigned short)s) << 16);
}

__global__ __launch_bounds__(256, 1) void rnncf_kernel(
    const float* __restrict__ lead,   // (NVEH, NT, 2)
    const float* __restrict__ inits,  // (NVEH, 2)
    const float* __restrict__ h0,     // (NVEH, H)
    const float* __restrict__ c0,     // (NVEH, H)
    const float* __restrict__ W,      // (3, 80)
    const float* __restrict__ U,      // (20, 80)
    const float* __restrict__ b,      // (80,)
    const float* __restrict__ Wd,     // (20,)
    const float* __restrict__ bd,     // (1,)
    float* __restrict__ out)
{
    // UT: 6 tiles x 16 rows x 32 k (bf16). Gate tiles T=0..4: row m =
    // gate(m&3) of item j=5*(m>>2)+T, scaled log2e (2log2e for g), with
    // the rank-1 wcn correction folded in: A' = A_scaled - wcn_row * a5.
    //   ko<5  -> U[5kq+ko][col]*scale - wcn*7*Wd[5kq+ko]
    //   ko==5 -> -wcn
    //   ko==6 -> kq<3 ? W[kq][col]*scale : b[col]*scale - wcn*biasK
    //   ko==7 -> 0
    // Tile 5 (acc row a5), rows with (m&3)==0: ko<5 -> 7*Wd[5kq+ko],
    // ko==5 -> 1.0, else 0 (biasK added in fp32). Other rows 0.
    __shared__ __attribute__((aligned(16))) short UT[96 * 32];

    const int tid  = threadIdx.x;
    const int lane = tid & 63;
    const int q    = lane >> 4;       // k-window / item-group
    const int c    = lane & 15;       // vehicle column
    const float L2E = 1.44269504f;
    const float N2L = -2.f * L2E;     // -2*log2(e)
    const float P2L =  2.f * L2E;
    const float IN2L = -0.34657359028f;   // 1/N2L
    const float bdv = bd[0];
    const float biasK = 7.f * bdv - 4.f;

    // ---- build UT (wcn folded into gate tiles) ----
    for (int idx = tid; idx < 96 * 32; idx += 256) {
        int row = idx >> 5, k = idx & 31;
        int T = row >> 4, m = row & 15;
        int kq = k >> 3, ko = k & 7;
        float v = 0.f;
        if (T < 5) {
            int g = m & 3, j = 5 * (m >> 2) + T;
            int col = g * 20 + j;
            float scale = (g == 2) ? (2.f * L2E) : L2E;
            float wcn = -(-0.001f * W[col] + 0.0025f * W[80 + col]) * scale;
            if      (ko < 5)             v = U[(5 * kq + ko) * 80 + col] * scale
                                           - wcn * 7.f * Wd[5 * kq + ko];
            else if (ko == 5)            v = -wcn;
            else if (ko == 6 && kq < 3)  v = W[kq * 80 + col] * scale;
            else if (ko == 6)            v = b[col] * scale - wcn * biasK;
        } else if ((m & 3) == 0) {
            if      (ko < 5)  v = 7.f * Wd[5 * kq + ko];
            else if (ko == 5) v = 1.f;
        }
        UT[idx] = f2bf(v);
    }

    const int veh = blockIdx.x * 64 + (tid >> 6) * 16 + c;

    // ---- per-item constants: items j = 5q+T ----
    float wd7[5], w7b[5];
#pragma unroll
    for (int T = 0; T < 5; ++T) {
        float w7 = 7.f * Wd[5 * q + T];
        wd7[T] = w7;
        w7b[T] = bf2f(f2bf(w7));
    }

    // ---- init: h0 -> B-frag, res partial, acc_{-1}; c0 -> scaled ----
    bf16x8 Bf = {0, 0, 0, 0, 0, 0, 0, 0};
    float cst2[5], hl[5];
    float rpart = 0.f, apart = 0.f;
#pragma unroll
    for (int T = 0; T < 5; ++T) {
        int j = 5 * q + T;
        float hv = h0[veh * H + j];
        cst2[T] = N2L * c0[veh * H + j];
        hl[T] = hv;
        short hb = f2bf(hv);
        float hi = bf2f(hb);
        Bf[T] = hb;
        rpart = __builtin_fmaf(hv, wd7[T], rpart);
        rpart = __builtin_fmaf(-hi, w7b[T], rpart);
        apart = __builtin_fmaf(hv, wd7[T], apart);
    }
    Bf[5] = f2bf(rpart);
    apart += __shfl_xor(apart, 16);
    apart += __shfl_xor(apart, 32);

    float pos = inits[veh * 2 + 0];
    float spd = inits[veh * 2 + 1];
    {
        float a = apart + biasK;          // acc_{-1}, exact fp32
        pos -= 0.1f * a;                  // virtual lagged state
        spd -= 0.1f * a;
    }

    // ---- x~_0 and lead pipeline (depth 2) ----
    const float2* lp0 = (const float2*)lead + (long)veh * NT;
    {
        float2 lu = lp0[0];
        float xv = (q == 0) ? (lu.x - pos) * 0.01f
                 : (q == 1) ? spd * 0.025f
                            : lu.y * 0.025f;
        if (q < 3) Bf[6] = f2bf(xv);
        else       Bf[6] = (short)0x3F80;   // one-slot (1.0 bf16)
    }
    float2 lA = lp0[1];
    float2 lB = lp0[2];

    __syncthreads();   // UT visibility; only barrier in the kernel

    // ---- loop-invariant A fragments (row c, k-slice q) ----
    bf16x8 A[6];
#pragma unroll
    for (int T = 0; T < 6; ++T)
        A[T] = *(const bf16x8*)&UT[(T * 16 + c) * 32 + q * 8];

    for (int t = 0; t < NT; ++t) {
        float2 lu = lA;                   // lead[t+1], loaded 2 iters ago
        lA = lB;
        int tn = t + 3; tn = (tn < NT) ? tn : NT - 1;
        lB = lp0[tn];                     // consumed 2 iters from now

        f32x4 zero = {0.f, 0.f, 0.f, 0.f};
        // acc tile FIRST: everything downstream gates on z5[0]
        f32x4 z5 = __builtin_amdgcn_mfma_f32_16x16x32_bf16(A[5], Bf, zero, 0, 0, 0);
        f32x4 z[5];
#pragma unroll
        for (int T = 0; T < 5; ++T)
            z[T] = __builtin_amdgcn_mfma_f32_16x16x32_bf16(A[T], Bf, zero, 0, 0, 0);

        // ---- acc_{t-1}: every lane, fp32-accurate ----
        float acc = z5[0] + biasK;
        pos = __builtin_fmaf(0.1f, acc, pos);
        spd = __builtin_fmaf(0.1f, acc, spd);
        if (q == 1 && t > 0)
            out[(size_t)(t - 1) * NVEH + veh] = pos;   // coalesced

        // ---- x~_{t+1} into own B-frag slot ----
        {
            float xv = (q == 0) ? (lu.x - pos) * 0.01f
                     : (q == 1) ? spd * 0.025f
                                : lu.y * 0.025f;
            if (q < 3) Bf[6] = f2bf(xv);
        }

        // ---- 5 items (j=5q+T): gates lane-local, correction pre-folded ----
        float r[5];
#pragma unroll
        for (int T = 0; T < 5; ++T) {
            float ei = EXP2(-z[T][0]);    // e^{-i_eff}
            float ef = EXP2(-z[T][1]);    // e^{-f_eff}
            float eg = EXP2(-z[T][2]);    // e^{-2g_eff}
            float eo = EXP2(-z[T][3]);    // e^{-o_eff}
            float pi = 1.f + ei, pf = 1.f + ef, pg = 1.f + eg, po = 1.f + eo;
            float pig = pi * pg;
            float R3  = RCP(pf * pig);    // 1/(pf*pi*pg)
            float uu  = __builtin_fmaf(P2L, eg, N2L);         // N2L*(1-eg)
            float c2  = R3 * __builtin_fmaf(pig, cst2[T], uu * pf);
            cst2[T] = c2;                                     // scaled c
            float ec  = EXP2(__builtin_fminf(c2, 80.f));      // e^{-2c}
            float Roc = RCP(po * (1.f + ec));
            float hh  = (1.f - ec) * Roc;                     // s(o)*tanh(c)
            hl[T] = hh;
            unsigned u = __builtin_bit_cast(unsigned, hh);
            unsigned rr = u + 0x7fffu + ((u >> 16) & 1u);     // RNE
            Bf[T] = (short)(rr >> 16);
            float hi = __builtin_bit_cast(float, rr & 0xffff0000u);
            r[T] = __builtin_fmaf(hh, wd7[T], -(hi * w7b[T]));
        }
        float rq = ((r[0] + r[1]) + (r[2] + r[3])) + r[4];
        Bf[5] = f2bf(rq);
    }

    // ---- tail: acc_255 exact from fp32 hl ----
    float ap = 0.f;
#pragma unroll
    for (int T = 0; T < 5; ++T) ap = __builtin_fmaf(hl[T], wd7[T], ap);
    ap += __shfl_xor(ap, 16);
    ap += __shfl_xor(ap, 32);
    float accF = ap + biasK;
    if (q == 1) out[(size_t)(NT - 1) * NVEH + veh] = pos + 0.1f * accF;
    if (q == 2) out[(size_t)NT * NVEH + veh]       = spd + 0.1f * accF;

    // ---- final h, c (c unscaled from cst2) ----
    const int oH = NT * NVEH + NVEH;
    const int oC = oH + NVEH * H;
#pragma unroll
    for (int T = 0; T < 5; ++T) {
        int j = 5 * q + T;
        out[oH + veh * H + j] = hl[T];
        out[oC + veh * H + j] = cst2[T] * IN2L;
    }
}

extern "C" void kernel_launch(void* const* d_in, const int* in_sizes, int n_in,
                              void* d_out, int out_size, void* d_ws, size_t ws_size,
                              hipStream_t stream) {
    const float* lead  = (const float*)d_in[0];
    const float* inits = (const float*)d_in[1];
    const float* h0    = (const float*)d_in[2];
    const float* c0    = (const float*)d_in[3];
    const float* W     = (const float*)d_in[4];
    const float* U     = (const float*)d_in[5];
    const float* b     = (const float*)d_in[6];
    const float* Wd    = (const float*)d_in[7];
    const float* bd    = (const float*)d_in[8];
    float* out = (float*)d_out;

    rnncf_kernel<<<NVEH / 64, 256, 0, stream>>>(lead, inits, h0, c0, W, U, b, Wd, bd, out);
}